// Round 1
// baseline (780.025 us; speedup 1.0000x reference)
//
#include <hip/hip_runtime.h>

#define N_NODES 100000
#define N_EDGES 3200000
#define F_IN 64
#define F_OUT 128

// One 64-lane wave per edge; lane = input feature index.
// Coalesced gather of source row, atomicAdd into destination row of A.
__global__ __launch_bounds__(256) void gcn_scatter(
    const float* __restrict__ node_embeds,   // [N, F_IN]
    const int*   __restrict__ edge_indices,  // [2, E] row0=dst, row1=src
    const float* __restrict__ edge_weights,  // [E]
    float*       __restrict__ A)             // [N, F_IN] accumulator (pre-zeroed)
{
    const int lane   = threadIdx.x & 63;
    const int wave   = (blockIdx.x * blockDim.x + threadIdx.x) >> 6;
    const int nWaves = (gridDim.x * blockDim.x) >> 6;

    for (int e = wave; e < N_EDGES; e += nWaves) {
        const int   dst = edge_indices[e];            // row 0
        const int   src = edge_indices[N_EDGES + e];  // row 1
        const float w   = edge_weights[e];
        const float v   = node_embeds[src * F_IN + lane] * w;
        atomicAdd(&A[dst * F_IN + lane], v);
    }
}

// One block per node; thread = output feature. A-row staged in LDS,
// W column read through L1 (W = 32 KB, fully cache-resident).
__global__ __launch_bounds__(128) void gcn_proj(
    const float* __restrict__ A,      // [N, F_IN]
    const float* __restrict__ W,      // [F_IN, F_OUT]
    const float* __restrict__ bias,   // [F_OUT]
    float*       __restrict__ out)    // [N, F_OUT]
{
    __shared__ float arow[F_IN];
    const int n = blockIdx.x;
    const int f = threadIdx.x;

    if (f < F_IN) arow[f] = A[n * F_IN + f];
    __syncthreads();

    float acc = bias[f];
    #pragma unroll
    for (int k = 0; k < F_IN; ++k) {
        acc = fmaf(arow[k], W[k * F_OUT + f], acc);
    }
    out[n * F_OUT + f] = fmaxf(acc, 0.0f);
}

extern "C" void kernel_launch(void* const* d_in, const int* in_sizes, int n_in,
                              void* d_out, int out_size, void* d_ws, size_t ws_size,
                              hipStream_t stream) {
    const float* node_embeds  = (const float*)d_in[0];
    const int*   edge_indices = (const int*)  d_in[1];
    const float* edge_weights = (const float*)d_in[2];
    const float* W            = (const float*)d_in[3];
    const float* bias         = (const float*)d_in[4];
    float*       out          = (float*)d_out;
    float*       A            = (float*)d_ws;   // N_NODES * F_IN floats = 25.6 MB

    hipMemsetAsync(A, 0, (size_t)N_NODES * F_IN * sizeof(float), stream);

    // Scatter: 4096 blocks x 256 threads = 16384 waves, grid-stride over edges.
    gcn_scatter<<<4096, 256, 0, stream>>>(node_embeds, edge_indices, edge_weights, A);

    // Projection: one block per node.
    gcn_proj<<<N_NODES, 128, 0, stream>>>(A, W, bias, out);
}